// Round 1
// baseline (1034.141 us; speedup 1.0000x reference)
//
#include <hip/hip_runtime.h>
#include <math.h>

// Problem constants (match reference)
#define S 2048
#define H 1024
#define NE 8
#define INTER 2048
#define ALPHA 1.702f
#define LIMIT 7.0f

// GEMM tiling
#define TM 64
#define TN 64
#define BK 16

// Workspace layout (bytes)
#define WS_COUNTS 0
#define WS_SLOTS  4096                       // int[NE][S]            = 64 KB
#define WS_W      (WS_SLOTS + NE*S*4)        // float[2*S]            = 16 KB
#define WS_ACT    (WS_W + 2*S*4)             // float[2*S][INTER]     = 32 MB

// ---------------------------------------------------------------------------
// Kernel 1: router. One 64-lane wave per token. Computes 8 logits, top-2,
// softmax over the two, scatters (slot -> expert list) with atomics.
// slot id = token*2 + k  (k = rank in top-2). act depends only on (token,
// expert) and top-2 experts are distinct, so no duplicated GEMM work.
// ---------------------------------------------------------------------------
__global__ __launch_bounds__(64) void router_kernel(
    const float* __restrict__ x, const float* __restrict__ rw,
    const float* __restrict__ rb, int* __restrict__ counts,
    int* __restrict__ slots, float* __restrict__ slot_w)
{
    int tok = blockIdx.x;
    int lane = threadIdx.x;
    float acc[NE];
#pragma unroll
    for (int e = 0; e < NE; ++e) acc[e] = 0.f;
    const float* xr = x + (size_t)tok * H;
    for (int h = lane; h < H; h += 64) {
        float xv = xr[h];
        const float* wr = rw + (size_t)h * NE;
#pragma unroll
        for (int e = 0; e < NE; ++e) acc[e] += xv * wr[e];
    }
#pragma unroll
    for (int e = 0; e < NE; ++e) {
#pragma unroll
        for (int off = 32; off > 0; off >>= 1)
            acc[e] += __shfl_down(acc[e], off);
    }
    if (lane == 0) {
        float v[NE];
#pragma unroll
        for (int e = 0; e < NE; ++e) v[e] = acc[e] + rb[e];
        int i1 = 0; float v1 = v[0];
#pragma unroll
        for (int e = 1; e < NE; ++e) if (v[e] > v1) { v1 = v[e]; i1 = e; }
        int i2 = -1; float v2 = -3.0e38f;
#pragma unroll
        for (int e = 0; e < NE; ++e) if (e != i1 && v[e] > v2) { v2 = v[e]; i2 = e; }
        // softmax over {v1, v2}, v1 >= v2
        float w1 = 1.f / (1.f + expf(v2 - v1));
        float w2 = 1.f - w1;
        int p1 = atomicAdd(&counts[i1], 1);
        slots[i1 * S + p1] = tok * 2;
        slot_w[tok * 2] = w1;
        int p2 = atomicAdd(&counts[i2], 1);
        slots[i2 * S + p2] = tok * 2 + 1;
        slot_w[tok * 2 + 1] = w2;
    }
}

// ---------------------------------------------------------------------------
// Kernel 2: grouped gate_up GEMM + fused activation.
// Per expert e: A = gathered x rows [cnt, H], B = gate_up_proj[e] [H, 2I].
// Tile 64x64, BK=16, 4x4 register blocking per thread (256 threads),
// gate and up columns computed together. Epilogue: bias + clamp + glu.
// ---------------------------------------------------------------------------
__global__ __launch_bounds__(256) void gateup_kernel(
    const float* __restrict__ x, const float* __restrict__ gup,
    const float* __restrict__ gub, const int* __restrict__ counts,
    const int* __restrict__ slots, float* __restrict__ act)
{
    int e = blockIdx.y;
    int cnt = counts[e];
    int mt = blockIdx.x / (INTER / TN);
    int nt = blockIdx.x % (INTER / TN);
    int m0 = mt * TM;
    if (m0 >= cnt) return;
    int n0 = nt * TN;

    __shared__ float As[BK][TM + 4];   // k-major, padded
    __shared__ float Bg[BK][TN];
    __shared__ float Bu[BK][TN];

    int t = threadIdx.x;
    int tx = t & 15, ty = t >> 4;

    // A staging: thread -> (m = t/4, 4 contiguous k)
    int am = t >> 2;
    int ak = (t & 3) << 2;
    int arow = m0 + am;
    int aslot = slots[e * S + (arow < cnt ? arow : cnt - 1)];
    const float* aptr = x + (size_t)(aslot >> 1) * H + ak;

    // B staging: thread -> (kk = t/16, 4 contiguous n)
    int bk = t >> 4;
    int bn = (t & 15) << 2;
    const float* gptr = gup + (size_t)e * H * 2 * INTER + (size_t)bk * 2 * INTER + n0 + bn;

    float accg[4][4] = {{0.f}}, accu[4][4] = {{0.f}};

    for (int k0 = 0; k0 < H; k0 += BK) {
        float4 av = *(const float4*)(aptr + k0);
        float4 gv = *(const float4*)(gptr + (size_t)k0 * 2 * INTER);
        float4 uv = *(const float4*)(gptr + (size_t)k0 * 2 * INTER + INTER);
        __syncthreads();  // protect previous iteration's LDS reads
        As[ak + 0][am] = av.x; As[ak + 1][am] = av.y;
        As[ak + 2][am] = av.z; As[ak + 3][am] = av.w;
        *(float4*)&Bg[bk][bn] = gv;
        *(float4*)&Bu[bk][bn] = uv;
        __syncthreads();
#pragma unroll
        for (int kk = 0; kk < BK; ++kk) {
            float4 a = *(const float4*)&As[kk][ty * 4];
            float4 g = *(const float4*)&Bg[kk][tx * 4];
            float4 u = *(const float4*)&Bu[kk][tx * 4];
            float aa[4] = {a.x, a.y, a.z, a.w};
            float gg[4] = {g.x, g.y, g.z, g.w};
            float uu[4] = {u.x, u.y, u.z, u.w};
#pragma unroll
            for (int i = 0; i < 4; ++i)
#pragma unroll
                for (int j = 0; j < 4; ++j) {
                    accg[i][j] += aa[i] * gg[j];
                    accu[i][j] += aa[i] * uu[j];
                }
        }
    }

#pragma unroll
    for (int i = 0; i < 4; ++i) {
        int row = m0 + ty * 4 + i;
        if (row >= cnt) continue;
        int slot = slots[e * S + row];
        float4 r;
#pragma unroll
        for (int j = 0; j < 4; ++j) {
            int n = n0 + tx * 4 + j;
            float gate = accg[i][j] + gub[(size_t)e * 2 * INTER + n];
            float up   = accu[i][j] + gub[(size_t)e * 2 * INTER + INTER + n];
            gate = fminf(gate, LIMIT);
            up = fminf(fmaxf(up, -LIMIT), LIMIT);
            float glu = gate / (1.f + expf(-ALPHA * gate));
            ((float*)&r)[j] = (up + 1.f) * glu;
        }
        *(float4*)(act + (size_t)slot * INTER + n0 + tx * 4) = r;
    }
}

// ---------------------------------------------------------------------------
// Kernel 3: grouped down GEMM + bias + weighted combine (atomicAdd into out).
// Per expert e: A = act rows [cnt, I], B = down_proj[e] [I, H].
// ---------------------------------------------------------------------------
__global__ __launch_bounds__(256) void down_kernel(
    const float* __restrict__ act, const float* __restrict__ dp,
    const float* __restrict__ db, const int* __restrict__ counts,
    const int* __restrict__ slots, const float* __restrict__ slot_w,
    float* __restrict__ out)
{
    int e = blockIdx.y;
    int cnt = counts[e];
    int mt = blockIdx.x / (H / TN);
    int nt = blockIdx.x % (H / TN);
    int m0 = mt * TM;
    if (m0 >= cnt) return;
    int n0 = nt * TN;

    __shared__ float As[BK][TM + 4];
    __shared__ float Bs[BK][TN];

    int t = threadIdx.x;
    int tx = t & 15, ty = t >> 4;

    int am = t >> 2;
    int ak = (t & 3) << 2;
    int arow = m0 + am;
    int aslot = slots[e * S + (arow < cnt ? arow : cnt - 1)];
    const float* aptr = act + (size_t)aslot * INTER + ak;

    int bk = t >> 4;
    int bn = (t & 15) << 2;
    const float* bptr = dp + (size_t)e * INTER * H + (size_t)bk * H + n0 + bn;

    float acc[4][4] = {{0.f}};

    for (int k0 = 0; k0 < INTER; k0 += BK) {
        float4 av = *(const float4*)(aptr + k0);
        float4 bv = *(const float4*)(bptr + (size_t)k0 * H);
        __syncthreads();
        As[ak + 0][am] = av.x; As[ak + 1][am] = av.y;
        As[ak + 2][am] = av.z; As[ak + 3][am] = av.w;
        *(float4*)&Bs[bk][bn] = bv;
        __syncthreads();
#pragma unroll
        for (int kk = 0; kk < BK; ++kk) {
            float4 a = *(const float4*)&As[kk][ty * 4];
            float4 b = *(const float4*)&Bs[kk][tx * 4];
            float aa[4] = {a.x, a.y, a.z, a.w};
            float bb[4] = {b.x, b.y, b.z, b.w};
#pragma unroll
            for (int i = 0; i < 4; ++i)
#pragma unroll
                for (int j = 0; j < 4; ++j)
                    acc[i][j] += aa[i] * bb[j];
        }
    }

#pragma unroll
    for (int i = 0; i < 4; ++i) {
        int row = m0 + ty * 4 + i;
        if (row >= cnt) continue;
        int slot = slots[e * S + row];
        int tok = slot >> 1;
        float w = slot_w[slot];
#pragma unroll
        for (int j = 0; j < 4; ++j) {
            int n = n0 + tx * 4 + j;
            float r = acc[i][j] + db[(size_t)e * H + n];
            atomicAdd(&out[(size_t)tok * H + n], w * r);
        }
    }
}

// ---------------------------------------------------------------------------
extern "C" void kernel_launch(void* const* d_in, const int* in_sizes, int n_in,
                              void* d_out, int out_size, void* d_ws, size_t ws_size,
                              hipStream_t stream)
{
    const float* x   = (const float*)d_in[0];
    const float* rw  = (const float*)d_in[1];
    const float* rb  = (const float*)d_in[2];
    const float* gup = (const float*)d_in[3];
    const float* gub = (const float*)d_in[4];
    const float* dp  = (const float*)d_in[5];
    const float* db  = (const float*)d_in[6];
    float* out = (float*)d_out;

    char* ws = (char*)d_ws;
    int* counts   = (int*)(ws + WS_COUNTS);
    int* slots    = (int*)(ws + WS_SLOTS);
    float* slot_w = (float*)(ws + WS_W);
    float* act    = (float*)(ws + WS_ACT);

    hipMemsetAsync(counts, 0, 4096, stream);
    hipMemsetAsync(out, 0, (size_t)S * H * sizeof(float), stream);

    router_kernel<<<S, 64, 0, stream>>>(x, rw, rb, counts, slots, slot_w);

    dim3 g1((S / TM) * (INTER / TN), NE);
    gateup_kernel<<<g1, 256, 0, stream>>>(x, gup, gub, counts, slots, act);

    dim3 g2((S / TM) * (H / TN), NE);
    down_kernel<<<g2, 256, 0, stream>>>(act, dp, db, counts, slots, slot_w, out);
}

// Round 2
// 481.246 us; speedup vs baseline: 2.1489x; 2.1489x over previous
//
#include <hip/hip_runtime.h>
#include <hip/hip_bf16.h>
#include <math.h>

// Problem constants
#define S 2048
#define H 1024
#define NE 8
#define INTER 2048
#define ALPHA 1.702f
#define LIMIT 7.0f

typedef __bf16 bf16x8 __attribute__((ext_vector_type(8)));
typedef float f32x4 __attribute__((ext_vector_type(4)));

// Workspace layout (bytes)
#define WS_COUNTS 0                                   // 4 KB
#define WS_SLOTS  4096                                // int[NE][S] = 64 KB
#define WS_W      (WS_SLOTS + NE*S*4)                 // float[2S] = 16 KB
#define WS_XB     (WS_W + 2*S*4)                      // bf16 x [S][H] = 4 MB
#define WS_GUP    (WS_XB + (size_t)S*H*2)             // bf16 [E][2][I][H] = 64 MB
#define WS_DPN    (WS_GUP + (size_t)NE*2*INTER*H*2)   // bf16 [E][H][I] = 32 MB
#define WS_ACT    (WS_DPN + (size_t)NE*H*INTER*2)     // bf16 [2S][I] = 16 MB

static __device__ __forceinline__ unsigned short f2bf(float f) {
    union { __hip_bfloat16 h; unsigned short u; } cv;
    cv.h = __float2bfloat16(f);
    return cv.u;
}

static __device__ __forceinline__ void gload16(const void* g, void* l) {
    __builtin_amdgcn_global_load_lds(
        (const __attribute__((address_space(1))) unsigned int*)(unsigned long long)g,
        (__attribute__((address_space(3))) unsigned int*)(unsigned int)(unsigned long long)l,
        16, 0, 0);
}

// ---------------------------------------------------------------------------
// Router: one wave per token, 8 logits, top-2 + softmax, scatter to lists.
// ---------------------------------------------------------------------------
__global__ __launch_bounds__(64) void router_kernel(
    const float* __restrict__ x, const float* __restrict__ rw,
    const float* __restrict__ rb, int* __restrict__ counts,
    int* __restrict__ slots, float* __restrict__ slot_w)
{
    int tok = blockIdx.x;
    int lane = threadIdx.x;
    float acc[NE];
#pragma unroll
    for (int e = 0; e < NE; ++e) acc[e] = 0.f;
    const float* xr = x + (size_t)tok * H;
    for (int h = lane; h < H; h += 64) {
        float xv = xr[h];
        const float* wr = rw + (size_t)h * NE;
#pragma unroll
        for (int e = 0; e < NE; ++e) acc[e] += xv * wr[e];
    }
#pragma unroll
    for (int e = 0; e < NE; ++e) {
#pragma unroll
        for (int off = 32; off > 0; off >>= 1)
            acc[e] += __shfl_down(acc[e], off);
    }
    if (lane == 0) {
        float v[NE];
#pragma unroll
        for (int e = 0; e < NE; ++e) v[e] = acc[e] + rb[e];
        int i1 = 0; float v1 = v[0];
#pragma unroll
        for (int e = 1; e < NE; ++e) if (v[e] > v1) { v1 = v[e]; i1 = e; }
        int i2 = -1; float v2 = -3.0e38f;
#pragma unroll
        for (int e = 0; e < NE; ++e) if (e != i1 && v[e] > v2) { v2 = v[e]; i2 = e; }
        float w1 = 1.f / (1.f + expf(v2 - v1));
        float w2 = 1.f - w1;
        int p1 = atomicAdd(&counts[i1], 1);
        slots[i1 * S + p1] = tok * 2;
        slot_w[tok * 2] = w1;
        int p2 = atomicAdd(&counts[i2], 1);
        slots[i2 * S + p2] = tok * 2 + 1;
        slot_w[tok * 2 + 1] = w2;
    }
}

// ---------------------------------------------------------------------------
// x fp32 -> bf16 straight copy. 4 elems/thread.
// ---------------------------------------------------------------------------
__global__ __launch_bounds__(256) void conv_x(const float* __restrict__ in,
                                              unsigned short* __restrict__ out)
{
    int i = blockIdx.x * 256 + threadIdx.x;
    float4 v = ((const float4*)in)[i];
    ushort4 o;
    o.x = f2bf(v.x); o.y = f2bf(v.y); o.z = f2bf(v.z); o.w = f2bf(v.w);
    ((ushort4*)out)[i] = o;
}

// ---------------------------------------------------------------------------
// Transpose + fp32->bf16: in logical [K][N] (row stride in_stride, col offset
// in_coloff) -> out [N][K]. 32x32 LDS tiles. grid: (K/32, N/32, Z).
// ---------------------------------------------------------------------------
__global__ __launch_bounds__(256) void transpose_bf16(
    const float* __restrict__ in, unsigned short* __restrict__ out,
    int K, int N, int in_stride, int in_coloff,
    size_t in_zstride, size_t out_zstride)
{
    __shared__ float tile[32][33];
    const float* ip = in + blockIdx.z * in_zstride;
    unsigned short* op = out + blockIdx.z * out_zstride;
    int k0 = blockIdx.x * 32, n0 = blockIdx.y * 32;
    int t = threadIdx.x;
    int lk = t >> 3, ln = (t & 7) * 4;
    float4 v = *(const float4*)(ip + (size_t)(k0 + lk) * in_stride + in_coloff + n0 + ln);
    tile[lk][ln + 0] = v.x; tile[lk][ln + 1] = v.y;
    tile[lk][ln + 2] = v.z; tile[lk][ln + 3] = v.w;
    __syncthreads();
    int on = t >> 3, ok = (t & 7) * 4;
    ushort4 o;
    o.x = f2bf(tile[ok + 0][on]); o.y = f2bf(tile[ok + 1][on]);
    o.z = f2bf(tile[ok + 2][on]); o.w = f2bf(tile[ok + 3][on]);
    *(ushort4*)(op + (size_t)(n0 + on) * K + k0 + ok) = o;
}

// ---------------------------------------------------------------------------
// Grouped gate_up MFMA GEMM + fused activation -> act (bf16).
// Tile M=128 (gathered token slots), N=64 (INTER cols, gate+up together),
// BK=32. 4 waves in 2x2; each wave: 4 m-frags x 2 n-frags x {g,u}.
// A: xb [tok][H] bf16; B: gw [e][2][INTER][H] bf16 n-major.
// ---------------------------------------------------------------------------
__global__ __launch_bounds__(256) void gateup_mfma(
    const unsigned short* __restrict__ xb,
    const unsigned short* __restrict__ gw,
    const float* __restrict__ gub,
    const int* __restrict__ counts, const int* __restrict__ slots,
    unsigned short* __restrict__ act)
{
    int e = blockIdx.z;
    int cnt = counts[e];
    int m0 = blockIdx.y * 128;
    if (m0 >= cnt) return;
    int n0 = blockIdx.x * 64;

    __shared__ unsigned short As[128 * 32];
    __shared__ unsigned short Gs[64 * 32];
    __shared__ unsigned short Us[64 * 32];
    __shared__ int sl[128];

    int t = threadIdx.x;
    int lane = t & 63, w = t >> 6;
    if (t < 128) {
        int r = m0 + t;
        sl[t] = slots[e * S + (r < cnt ? r : cnt - 1)];
    }
    __syncthreads();

    int quad = lane >> 4, l16 = lane & 15;
    int wm = (w >> 1) * 64, wn = (w & 1) * 32;

    // staging: wave w stages A rows w*32 .. w*32+31 (two 16-row chunks),
    // and B rows w*16 .. w*16+15 of each of Gs/Us.
    int ar0 = w * 32 + (lane >> 2);
    int ar1 = ar0 + 16;
    const unsigned short* ap0 = xb + (size_t)(sl[ar0] >> 1) * H + (lane & 3) * 8;
    const unsigned short* ap1 = xb + (size_t)(sl[ar1] >> 1) * H + (lane & 3) * 8;
    int bn = w * 16 + (lane >> 2);
    const unsigned short* gp = gw + (size_t)e * 2 * INTER * H + (size_t)(n0 + bn) * H + (lane & 3) * 8;
    const unsigned short* up = gp + (size_t)INTER * H;

    unsigned short* la0 = &As[(2 * w) * 512 + lane * 8];
    unsigned short* la1 = &As[(2 * w + 1) * 512 + lane * 8];
    unsigned short* lg = &Gs[w * 512 + lane * 8];
    unsigned short* lu = &Us[w * 512 + lane * 8];

    f32x4 accg[4][2], accu[4][2];
#pragma unroll
    for (int mi = 0; mi < 4; ++mi)
#pragma unroll
        for (int ni = 0; ni < 2; ++ni) {
            accg[mi][ni] = (f32x4){0.f, 0.f, 0.f, 0.f};
            accu[mi][ni] = (f32x4){0.f, 0.f, 0.f, 0.f};
        }

    for (int k0 = 0; k0 < H; k0 += 32) {
        __syncthreads();
        gload16(ap0 + k0, la0);
        gload16(ap1 + k0, la1);
        gload16(gp + k0, lg);
        gload16(up + k0, lu);
        __syncthreads();
        bf16x8 af[4], gf[2], uf[2];
#pragma unroll
        for (int mi = 0; mi < 4; ++mi)
            af[mi] = *(const bf16x8*)&As[(wm + mi * 16 + l16) * 32 + quad * 8];
#pragma unroll
        for (int ni = 0; ni < 2; ++ni) {
            gf[ni] = *(const bf16x8*)&Gs[(wn + ni * 16 + l16) * 32 + quad * 8];
            uf[ni] = *(const bf16x8*)&Us[(wn + ni * 16 + l16) * 32 + quad * 8];
        }
#pragma unroll
        for (int mi = 0; mi < 4; ++mi)
#pragma unroll
            for (int ni = 0; ni < 2; ++ni) {
                accg[mi][ni] = __builtin_amdgcn_mfma_f32_16x16x32_bf16(af[mi], gf[ni], accg[mi][ni], 0, 0, 0);
                accu[mi][ni] = __builtin_amdgcn_mfma_f32_16x16x32_bf16(af[mi], uf[ni], accu[mi][ni], 0, 0, 0);
            }
    }

    // epilogue: C/D layout col=lane&15, row=quad*4+reg (verified m89/m91)
    const float* gb = gub + (size_t)e * 2 * INTER;
#pragma unroll
    for (int mi = 0; mi < 4; ++mi) {
#pragma unroll
        for (int r = 0; r < 4; ++r) {
            int rt = wm + mi * 16 + quad * 4 + r;
            if (m0 + rt >= cnt) continue;
            int slot = sl[rt];
            unsigned short* orow = act + (size_t)slot * INTER;
#pragma unroll
            for (int ni = 0; ni < 2; ++ni) {
                int col = n0 + wn + ni * 16 + l16;
                float gate = accg[mi][ni][r] + gb[col];
                float uv = accu[mi][ni][r] + gb[INTER + col];
                gate = fminf(gate, LIMIT);
                uv = fminf(fmaxf(uv, -LIMIT), LIMIT);
                float glu = gate / (1.f + __expf(-ALPHA * gate));
                orow[col] = f2bf((uv + 1.f) * glu);
            }
        }
    }
}

// ---------------------------------------------------------------------------
// Grouped down MFMA GEMM + bias + weighted combine (atomicAdd).
// A: act [slot][I] bf16; B: dw [e][H][I] bf16 n-major. Tile 128x64, BK=32.
// ---------------------------------------------------------------------------
__global__ __launch_bounds__(256) void down_mfma(
    const unsigned short* __restrict__ act,
    const unsigned short* __restrict__ dw,
    const float* __restrict__ db,
    const int* __restrict__ counts, const int* __restrict__ slots,
    const float* __restrict__ slot_w,
    float* __restrict__ out)
{
    int e = blockIdx.z;
    int cnt = counts[e];
    int m0 = blockIdx.y * 128;
    if (m0 >= cnt) return;
    int n0 = blockIdx.x * 64;

    __shared__ unsigned short As[128 * 32];
    __shared__ unsigned short Bs[64 * 32];
    __shared__ int sl[128];

    int t = threadIdx.x;
    int lane = t & 63, w = t >> 6;
    if (t < 128) {
        int r = m0 + t;
        sl[t] = slots[e * S + (r < cnt ? r : cnt - 1)];
    }
    __syncthreads();

    int quad = lane >> 4, l16 = lane & 15;
    int wm = (w >> 1) * 64, wn = (w & 1) * 32;

    int ar0 = w * 32 + (lane >> 2);
    int ar1 = ar0 + 16;
    const unsigned short* ap0 = act + (size_t)sl[ar0] * INTER + (lane & 3) * 8;
    const unsigned short* ap1 = act + (size_t)sl[ar1] * INTER + (lane & 3) * 8;
    int bn = w * 16 + (lane >> 2);
    const unsigned short* bp = dw + (size_t)e * H * INTER + (size_t)(n0 + bn) * INTER + (lane & 3) * 8;

    unsigned short* la0 = &As[(2 * w) * 512 + lane * 8];
    unsigned short* la1 = &As[(2 * w + 1) * 512 + lane * 8];
    unsigned short* lb = &Bs[w * 512 + lane * 8];

    f32x4 acc[4][2];
#pragma unroll
    for (int mi = 0; mi < 4; ++mi)
#pragma unroll
        for (int ni = 0; ni < 2; ++ni)
            acc[mi][ni] = (f32x4){0.f, 0.f, 0.f, 0.f};

    for (int k0 = 0; k0 < INTER; k0 += 32) {
        __syncthreads();
        gload16(ap0 + k0, la0);
        gload16(ap1 + k0, la1);
        gload16(bp + k0, lb);
        __syncthreads();
        bf16x8 af[4], bf[2];
#pragma unroll
        for (int mi = 0; mi < 4; ++mi)
            af[mi] = *(const bf16x8*)&As[(wm + mi * 16 + l16) * 32 + quad * 8];
#pragma unroll
        for (int ni = 0; ni < 2; ++ni)
            bf[ni] = *(const bf16x8*)&Bs[(wn + ni * 16 + l16) * 32 + quad * 8];
#pragma unroll
        for (int mi = 0; mi < 4; ++mi)
#pragma unroll
            for (int ni = 0; ni < 2; ++ni)
                acc[mi][ni] = __builtin_amdgcn_mfma_f32_16x16x32_bf16(af[mi], bf[ni], acc[mi][ni], 0, 0, 0);
    }

    const float* dbr = db + (size_t)e * H;
#pragma unroll
    for (int mi = 0; mi < 4; ++mi) {
#pragma unroll
        for (int r = 0; r < 4; ++r) {
            int rt = wm + mi * 16 + quad * 4 + r;
            if (m0 + rt >= cnt) continue;
            int slot = sl[rt];
            int tok = slot >> 1;
            float wgt = slot_w[slot];
#pragma unroll
            for (int ni = 0; ni < 2; ++ni) {
                int col = n0 + wn + ni * 16 + l16;
                float rr = acc[mi][ni][r] + dbr[col];
                atomicAdd(&out[(size_t)tok * H + col], wgt * rr);
            }
        }
    }
}

// ---------------------------------------------------------------------------
extern "C" void kernel_launch(void* const* d_in, const int* in_sizes, int n_in,
                              void* d_out, int out_size, void* d_ws, size_t ws_size,
                              hipStream_t stream)
{
    const float* x   = (const float*)d_in[0];
    const float* rw  = (const float*)d_in[1];
    const float* rb  = (const float*)d_in[2];
    const float* gup = (const float*)d_in[3];
    const float* gub = (const float*)d_in[4];
    const float* dp  = (const float*)d_in[5];
    const float* db  = (const float*)d_in[6];
    float* out = (float*)d_out;

    char* ws = (char*)d_ws;
    int* counts            = (int*)(ws + WS_COUNTS);
    int* slots             = (int*)(ws + WS_SLOTS);
    float* slot_w          = (float*)(ws + WS_W);
    unsigned short* xb     = (unsigned short*)(ws + WS_XB);
    unsigned short* gw     = (unsigned short*)(ws + WS_GUP);
    unsigned short* dw     = (unsigned short*)(ws + WS_DPN);
    unsigned short* act    = (unsigned short*)(ws + WS_ACT);

    hipMemsetAsync(counts, 0, 4096, stream);
    hipMemsetAsync(out, 0, (size_t)S * H * sizeof(float), stream);

    // conversions
    conv_x<<<(S * H) / (256 * 4), 256, 0, stream>>>(x, xb);
    // gate half: in [e][1024][4096] cols 0..2047 -> gw[e*2+0][n][k]
    transpose_bf16<<<dim3(H / 32, INTER / 32, NE), 256, 0, stream>>>(
        gup, gw, H, INTER, 2 * INTER, 0,
        (size_t)H * 2 * INTER, (size_t)2 * INTER * H);
    // up half: cols 2048..4095 -> gw[e*2+1][n][k]
    transpose_bf16<<<dim3(H / 32, INTER / 32, NE), 256, 0, stream>>>(
        gup, gw + (size_t)INTER * H, H, INTER, 2 * INTER, INTER,
        (size_t)H * 2 * INTER, (size_t)2 * INTER * H);
    // down: in [e][2048][1024] -> dw [e][1024][2048]
    transpose_bf16<<<dim3(INTER / 32, H / 32, NE), 256, 0, stream>>>(
        dp, dw, INTER, H, H, 0,
        (size_t)INTER * H, (size_t)H * INTER);

    router_kernel<<<S, 64, 0, stream>>>(x, rw, rb, counts, slots, slot_w);

    gateup_mfma<<<dim3(INTER / 64, 16, NE), 256, 0, stream>>>(
        xb, gw, gub, counts, slots, act);

    down_mfma<<<dim3(H / 64, 16, NE), 256, 0, stream>>>(
        act, dw, db, counts, slots, slot_w, out);
}

// Round 3
// 450.719 us; speedup vs baseline: 2.2944x; 1.0677x over previous
//
#include <hip/hip_runtime.h>
#include <hip/hip_bf16.h>
#include <math.h>

// Problem constants
#define S 2048
#define H 1024
#define NE 8
#define INTER 2048
#define ALPHA 1.702f
#define LIMIT 7.0f

typedef __bf16 bf16x8 __attribute__((ext_vector_type(8)));
typedef float f32x4 __attribute__((ext_vector_type(4)));
typedef unsigned short u16x8 __attribute__((ext_vector_type(8)));

// Workspace layout (bytes)
#define WS_COUNTS 0                                   // 4 KB
#define WS_SLOTS  4096                                // int[NE][S] = 64 KB
#define WS_W      (WS_SLOTS + NE*S*4)                 // float[2S] = 16 KB
#define WS_XB     (WS_W + 2*S*4)                      // bf16 x [S][H] = 4 MB
#define WS_GUP    (WS_XB + (size_t)S*H*2)             // bf16 [E][2][I][H] = 64 MB
#define WS_DPN    (WS_GUP + (size_t)NE*2*INTER*H*2)   // bf16 [E][H][I] = 32 MB
#define WS_ACT    (WS_DPN + (size_t)NE*H*INTER*2)     // bf16 [2S][I] = 16 MB

static __device__ __forceinline__ unsigned short f2bf(float f) {
    union { __hip_bfloat16 h; unsigned short u; } cv;
    cv.h = __float2bfloat16(f);
    return cv.u;
}

static __device__ __forceinline__ void gload16(const void* g, void* l) {
    __builtin_amdgcn_global_load_lds(
        (const __attribute__((address_space(1))) unsigned int*)(unsigned long long)g,
        (__attribute__((address_space(3))) unsigned int*)(unsigned int)(unsigned long long)l,
        16, 0, 0);
}

// ---------------------------------------------------------------------------
// Router + x->bf16 conversion. One wave per token. float4 loads of the token
// row (also converted and stored to xb), 8 logits, top-2 + softmax, scatter.
// ---------------------------------------------------------------------------
__global__ __launch_bounds__(64) void router_conv(
    const float* __restrict__ x, const float* __restrict__ rw,
    const float* __restrict__ rb, int* __restrict__ counts,
    int* __restrict__ slots, float* __restrict__ slot_w,
    unsigned short* __restrict__ xb)
{
    int tok = blockIdx.x;
    int lane = threadIdx.x;
    const float4* xr = (const float4*)(x + (size_t)tok * H);
    ushort4* xo = (ushort4*)(xb + (size_t)tok * H);
    float acc[NE];
#pragma unroll
    for (int e = 0; e < NE; ++e) acc[e] = 0.f;
#pragma unroll
    for (int p = 0; p < H / 256; ++p) {
        int idx = p * 64 + lane;          // float4 index; h = idx*4
        float4 v = xr[idx];
        ushort4 o;
        o.x = f2bf(v.x); o.y = f2bf(v.y); o.z = f2bf(v.z); o.w = f2bf(v.w);
        xo[idx] = o;
        const float* wr = rw + (size_t)idx * 4 * NE;
#pragma unroll
        for (int e = 0; e < NE; ++e)
            acc[e] += v.x * wr[e] + v.y * wr[NE + e] + v.z * wr[2 * NE + e] + v.w * wr[3 * NE + e];
    }
#pragma unroll
    for (int e = 0; e < NE; ++e) {
#pragma unroll
        for (int off = 32; off > 0; off >>= 1)
            acc[e] += __shfl_down(acc[e], off);
    }
    if (lane == 0) {
        float v[NE];
#pragma unroll
        for (int e = 0; e < NE; ++e) v[e] = acc[e] + rb[e];
        int i1 = 0; float v1 = v[0];
#pragma unroll
        for (int e = 1; e < NE; ++e) if (v[e] > v1) { v1 = v[e]; i1 = e; }
        int i2 = -1; float v2 = -3.0e38f;
#pragma unroll
        for (int e = 0; e < NE; ++e) if (e != i1 && v[e] > v2) { v2 = v[e]; i2 = e; }
        float w1 = 1.f / (1.f + expf(v2 - v1));
        float w2 = 1.f - w1;
        int p1 = atomicAdd(&counts[i1], 1);
        slots[i1 * S + p1] = tok * 2;
        slot_w[tok * 2] = w1;
        int p2 = atomicAdd(&counts[i2], 1);
        slots[i2 * S + p2] = tok * 2 + 1;
        slot_w[tok * 2 + 1] = w2;
    }
}

// ---------------------------------------------------------------------------
// Fused weight prep: fp32 [K][N] (row stride istride) -> bf16 [N][K].
// One launch covers gate half, up half, and down_proj for all experts.
// 64x64 tiles via LDS; reads float4-coalesced, writes ushort8 (128B/8 lanes).
// grid: (K/64 * N/64, NE*3)
// ---------------------------------------------------------------------------
__global__ __launch_bounds__(256) void prep(
    const float* __restrict__ gup, const float* __restrict__ dp,
    unsigned short* __restrict__ gw, unsigned short* __restrict__ dw)
{
    int z = blockIdx.y;
    int e = z / 3, which = z % 3;
    const float* in;
    unsigned short* out;
    int K, N, istride;
    if (which == 0) {
        in = gup + (size_t)e * H * 2 * INTER;
        out = gw + (size_t)e * 2 * INTER * H;
        K = H; N = INTER; istride = 2 * INTER;
    } else if (which == 1) {
        in = gup + (size_t)e * H * 2 * INTER + INTER;
        out = gw + (size_t)e * 2 * INTER * H + (size_t)INTER * H;
        K = H; N = INTER; istride = 2 * INTER;
    } else {
        in = dp + (size_t)e * INTER * H;
        out = dw + (size_t)e * H * INTER;
        K = INTER; N = H; istride = H;
    }
    int ntiles = N / 64;
    int k0 = (blockIdx.x / ntiles) * 64;
    int n0 = (blockIdx.x % ntiles) * 64;

    __shared__ unsigned short tile[64][68];   // [k][n], pad 68 keeps 8B align
    int t = threadIdx.x;
    int lk = t >> 4, ln = (t & 15) * 4;
#pragma unroll
    for (int p = 0; p < 4; ++p) {
        int kk = lk + p * 16;
        float4 v = *(const float4*)(in + (size_t)(k0 + kk) * istride + n0 + ln);
        ushort4 o;
        o.x = f2bf(v.x); o.y = f2bf(v.y); o.z = f2bf(v.z); o.w = f2bf(v.w);
        *(ushort4*)&tile[kk][ln] = o;
    }
    __syncthreads();
    int wn = t >> 3, wk = (t & 7) * 8;
#pragma unroll
    for (int p = 0; p < 2; ++p) {
        int nn = wn + p * 32;
        u16x8 o;
#pragma unroll
        for (int i = 0; i < 8; ++i) o[i] = tile[wk + i][nn];
        *(u16x8*)(out + (size_t)(n0 + nn) * K + k0 + wk) = o;
    }
}

// ---------------------------------------------------------------------------
// Grouped gate_up MFMA GEMM + fused activation -> act (bf16).
// Tile M=128 x N=64 (gate+up together), BK=32, 4 waves 2x2.
// ---------------------------------------------------------------------------
__global__ __launch_bounds__(256) void gateup_mfma(
    const unsigned short* __restrict__ xb,
    const unsigned short* __restrict__ gw,
    const float* __restrict__ gub,
    const int* __restrict__ counts, const int* __restrict__ slots,
    unsigned short* __restrict__ act)
{
    int e = blockIdx.z;
    int cnt = counts[e];
    int m0 = blockIdx.y * 128;
    if (m0 >= cnt) return;
    int n0 = blockIdx.x * 64;

    __shared__ unsigned short As[128 * 32];
    __shared__ unsigned short Gs[64 * 32];
    __shared__ unsigned short Us[64 * 32];
    __shared__ int sl[128];

    int t = threadIdx.x;
    int lane = t & 63, w = t >> 6;
    if (t < 128) {
        int r = m0 + t;
        sl[t] = slots[e * S + (r < cnt ? r : cnt - 1)];
    }
    __syncthreads();

    int quad = lane >> 4, l16 = lane & 15;
    int wm = (w >> 1) * 64, wn = (w & 1) * 32;

    int ar0 = w * 32 + (lane >> 2);
    int ar1 = ar0 + 16;
    const unsigned short* ap0 = xb + (size_t)(sl[ar0] >> 1) * H + (lane & 3) * 8;
    const unsigned short* ap1 = xb + (size_t)(sl[ar1] >> 1) * H + (lane & 3) * 8;
    int bn = w * 16 + (lane >> 2);
    const unsigned short* gp = gw + (size_t)e * 2 * INTER * H + (size_t)(n0 + bn) * H + (lane & 3) * 8;
    const unsigned short* up = gp + (size_t)INTER * H;

    unsigned short* la0 = &As[(2 * w) * 512 + lane * 8];
    unsigned short* la1 = &As[(2 * w + 1) * 512 + lane * 8];
    unsigned short* lg = &Gs[w * 512 + lane * 8];
    unsigned short* lu = &Us[w * 512 + lane * 8];

    f32x4 accg[4][2], accu[4][2];
#pragma unroll
    for (int mi = 0; mi < 4; ++mi)
#pragma unroll
        for (int ni = 0; ni < 2; ++ni) {
            accg[mi][ni] = (f32x4){0.f, 0.f, 0.f, 0.f};
            accu[mi][ni] = (f32x4){0.f, 0.f, 0.f, 0.f};
        }

    for (int k0 = 0; k0 < H; k0 += 32) {
        __syncthreads();
        gload16(ap0 + k0, la0);
        gload16(ap1 + k0, la1);
        gload16(gp + k0, lg);
        gload16(up + k0, lu);
        __syncthreads();
        bf16x8 af[4], gf[2], uf[2];
#pragma unroll
        for (int mi = 0; mi < 4; ++mi)
            af[mi] = *(const bf16x8*)&As[(wm + mi * 16 + l16) * 32 + quad * 8];
#pragma unroll
        for (int ni = 0; ni < 2; ++ni) {
            gf[ni] = *(const bf16x8*)&Gs[(wn + ni * 16 + l16) * 32 + quad * 8];
            uf[ni] = *(const bf16x8*)&Us[(wn + ni * 16 + l16) * 32 + quad * 8];
        }
#pragma unroll
        for (int mi = 0; mi < 4; ++mi)
#pragma unroll
            for (int ni = 0; ni < 2; ++ni) {
                accg[mi][ni] = __builtin_amdgcn_mfma_f32_16x16x32_bf16(af[mi], gf[ni], accg[mi][ni], 0, 0, 0);
                accu[mi][ni] = __builtin_amdgcn_mfma_f32_16x16x32_bf16(af[mi], uf[ni], accu[mi][ni], 0, 0, 0);
            }
    }

    const float* gb = gub + (size_t)e * 2 * INTER;
#pragma unroll
    for (int mi = 0; mi < 4; ++mi) {
#pragma unroll
        for (int r = 0; r < 4; ++r) {
            int rt = wm + mi * 16 + quad * 4 + r;
            if (m0 + rt >= cnt) continue;
            int slot = sl[rt];
            unsigned short* orow = act + (size_t)slot * INTER;
#pragma unroll
            for (int ni = 0; ni < 2; ++ni) {
                int col = n0 + wn + ni * 16 + l16;
                float gate = accg[mi][ni][r] + gb[col];
                float uv = accu[mi][ni][r] + gb[INTER + col];
                gate = fminf(gate, LIMIT);
                uv = fminf(fmaxf(uv, -LIMIT), LIMIT);
                float glu = gate / (1.f + __expf(-ALPHA * gate));
                orow[col] = f2bf((uv + 1.f) * glu);
            }
        }
    }
}

// ---------------------------------------------------------------------------
// Grouped down MFMA GEMM + bias + weighted combine. K-split 2 for occupancy:
// grid.z = e*2 + ks; each chunk does K in [ks*1024, ks*1024+1024) and
// atomicAdds its weighted partial (bias added by ks==0 only).
// ---------------------------------------------------------------------------
__global__ __launch_bounds__(256) void down_mfma(
    const unsigned short* __restrict__ act,
    const unsigned short* __restrict__ dw,
    const float* __restrict__ db,
    const int* __restrict__ counts, const int* __restrict__ slots,
    const float* __restrict__ slot_w,
    float* __restrict__ out)
{
    int e = blockIdx.z >> 1;
    int ks = blockIdx.z & 1;
    int cnt = counts[e];
    int m0 = blockIdx.y * 128;
    if (m0 >= cnt) return;
    int n0 = blockIdx.x * 64;

    __shared__ unsigned short As[128 * 32];
    __shared__ unsigned short Bs[64 * 32];
    __shared__ int sl[128];

    int t = threadIdx.x;
    int lane = t & 63, w = t >> 6;
    if (t < 128) {
        int r = m0 + t;
        sl[t] = slots[e * S + (r < cnt ? r : cnt - 1)];
    }
    __syncthreads();

    int quad = lane >> 4, l16 = lane & 15;
    int wm = (w >> 1) * 64, wn = (w & 1) * 32;

    int ar0 = w * 32 + (lane >> 2);
    int ar1 = ar0 + 16;
    int kbase = ks * (INTER / 2);
    const unsigned short* ap0 = act + (size_t)sl[ar0] * INTER + kbase + (lane & 3) * 8;
    const unsigned short* ap1 = act + (size_t)sl[ar1] * INTER + kbase + (lane & 3) * 8;
    int bn = w * 16 + (lane >> 2);
    const unsigned short* bp = dw + (size_t)e * H * INTER + (size_t)(n0 + bn) * INTER + kbase + (lane & 3) * 8;

    unsigned short* la0 = &As[(2 * w) * 512 + lane * 8];
    unsigned short* la1 = &As[(2 * w + 1) * 512 + lane * 8];
    unsigned short* lb = &Bs[w * 512 + lane * 8];

    f32x4 acc[4][2];
#pragma unroll
    for (int mi = 0; mi < 4; ++mi)
#pragma unroll
        for (int ni = 0; ni < 2; ++ni)
            acc[mi][ni] = (f32x4){0.f, 0.f, 0.f, 0.f};

    for (int k0 = 0; k0 < INTER / 2; k0 += 32) {
        __syncthreads();
        gload16(ap0 + k0, la0);
        gload16(ap1 + k0, la1);
        gload16(bp + k0, lb);
        __syncthreads();
        bf16x8 af[4], bf[2];
#pragma unroll
        for (int mi = 0; mi < 4; ++mi)
            af[mi] = *(const bf16x8*)&As[(wm + mi * 16 + l16) * 32 + quad * 8];
#pragma unroll
        for (int ni = 0; ni < 2; ++ni)
            bf[ni] = *(const bf16x8*)&Bs[(wn + ni * 16 + l16) * 32 + quad * 8];
#pragma unroll
        for (int mi = 0; mi < 4; ++mi)
#pragma unroll
            for (int ni = 0; ni < 2; ++ni)
                acc[mi][ni] = __builtin_amdgcn_mfma_f32_16x16x32_bf16(af[mi], bf[ni], acc[mi][ni], 0, 0, 0);
    }

    const float* dbr = db + (size_t)e * H;
#pragma unroll
    for (int mi = 0; mi < 4; ++mi) {
#pragma unroll
        for (int r = 0; r < 4; ++r) {
            int rt = wm + mi * 16 + quad * 4 + r;
            if (m0 + rt >= cnt) continue;
            int slot = sl[rt];
            int tok = slot >> 1;
            float wgt = slot_w[slot];
#pragma unroll
            for (int ni = 0; ni < 2; ++ni) {
                int col = n0 + wn + ni * 16 + l16;
                float rr = acc[mi][ni][r] + (ks == 0 ? dbr[col] : 0.f);
                atomicAdd(&out[(size_t)tok * H + col], wgt * rr);
            }
        }
    }
}

// ---------------------------------------------------------------------------
extern "C" void kernel_launch(void* const* d_in, const int* in_sizes, int n_in,
                              void* d_out, int out_size, void* d_ws, size_t ws_size,
                              hipStream_t stream)
{
    const float* x   = (const float*)d_in[0];
    const float* rw  = (const float*)d_in[1];
    const float* rb  = (const float*)d_in[2];
    const float* gup = (const float*)d_in[3];
    const float* gub = (const float*)d_in[4];
    const float* dp  = (const float*)d_in[5];
    const float* db  = (const float*)d_in[6];
    float* out = (float*)d_out;

    char* ws = (char*)d_ws;
    int* counts            = (int*)(ws + WS_COUNTS);
    int* slots             = (int*)(ws + WS_SLOTS);
    float* slot_w          = (float*)(ws + WS_W);
    unsigned short* xb     = (unsigned short*)(ws + WS_XB);
    unsigned short* gw     = (unsigned short*)(ws + WS_GUP);
    unsigned short* dw     = (unsigned short*)(ws + WS_DPN);
    unsigned short* act    = (unsigned short*)(ws + WS_ACT);

    hipMemsetAsync(counts, 0, 4096, stream);
    hipMemsetAsync(out, 0, (size_t)S * H * sizeof(float), stream);

    router_conv<<<S, 64, 0, stream>>>(x, rw, rb, counts, slots, slot_w, xb);

    // 512 tiles per (expert, tensor-piece): gate/up: 16k x 32n; down: 32k x 16n
    prep<<<dim3(512, NE * 3), 256, 0, stream>>>(gup, dp, gw, dw);

    gateup_mfma<<<dim3(INTER / 64, 16, NE), 256, 0, stream>>>(
        xb, gw, gub, counts, slots, act);

    down_mfma<<<dim3(H / 64, 16, NE * 2), 256, 0, stream>>>(
        act, dw, db, counts, slots, slot_w, out);
}